// Round 8
// baseline (1060.377 us; speedup 1.0000x reference)
//
#include <hip/hip_runtime.h>
#include <stdint.h>
#include <math.h>

// Match numpy's non-fused multiply-add rounding in distance/plane tests.
// All d2 / plane expressions keep exactly these forms (contract off file-wide);
// p2 everywhere is x*x+y*y+z*z — bit-identical to reference. The AABB
// classification is a conservative ROUTER only (outward-quantized boxes,
// SLACK >> fp error): every consumed value comes from exact per-point forms.
#pragma clang fp contract(off)

#define BLOCK 1024
#define NW 16                   // waves per block
#define MAX_ITERS 50
#define SOLO_CAP 2048
#define NBINS 32768             // 32^3 Morton bins
#define EPS_NORM 1e-8f
#define EPS_SEP (-1e-6f)
#define SLACK 1e-3f             // classify margin >> ~1e-5 fp error
#define QSC 2048.0f             // u16 quant: [-16,16] -> [0,65535]
#define QIN (1.0f/2048.0f)

// R13 post-mortem of R7: AABB classify at 512-pt chunk granularity bought 0
// (chunk AABB ~1-2 units -> band covers most live points -> everything
// "straddles"). Granularity is the knob: 64-pt groups on a 32^3 sort give
// extent ~0.3-0.5, tightening each rescan. Per-group LDS state (live bits,
// u16 outward-quantized AABB w/ sentinel, cached dmin/imin/count); per iter:
// lane-parallel classify -> all-die wholesale, boundary list compacted;
// waves rescan boundary groups 2-in-flight (coalesced 1KB float4 loads).
// Kills both the Sum(live)/iter load floor AND the 16-stride finish bank
// conflicts (781k in R7).
__device__ __forceinline__ int bin_of(float x, float y, float z) {
    int cx = (int)floorf((x + 3.5f) * (32.0f / 7.0f));
    int cy = (int)floorf((y + 3.5f) * (32.0f / 7.0f));
    int cz = (int)floorf((z + 3.5f) * (32.0f / 7.0f));
    cx = cx < 0 ? 0 : (cx > 31 ? 31 : cx);
    cy = cy < 0 ? 0 : (cy > 31 ? 31 : cy);
    cz = cz < 0 ? 0 : (cz > 31 ? 31 : cz);
    int code = 0;
    #pragma unroll
    for (int b = 0; b < 5; ++b) {
        code |= ((cx >> b) & 1) << (3 * b);
        code |= ((cy >> b) & 1) << (3 * b + 1);
        code |= ((cz >> b) & 1) << (3 * b + 2);
    }
    return code;
}

__global__ void hist_bins(const float* __restrict__ pc, int* __restrict__ binCnt,
                          int N) {
    const int t = blockIdx.x * blockDim.x + threadIdx.x;
    const int base = t * 4;
    if (base + 3 < N) {
        const float4* p4 = (const float4*)pc;       // 3 dwordx4 = 4 points
        const float4 a = p4[3*t+0], b = p4[3*t+1], c = p4[3*t+2];
        atomicAdd(&binCnt[bin_of(a.x, a.y, a.z)], 1);
        atomicAdd(&binCnt[bin_of(a.w, b.x, b.y)], 1);
        atomicAdd(&binCnt[bin_of(b.z, b.w, c.x)], 1);
        atomicAdd(&binCnt[bin_of(c.y, c.z, c.w)], 1);
    } else {
        for (int i = base; i < N; ++i)
            atomicAdd(&binCnt[bin_of(pc[3*i], pc[3*i+1], pc[3*i+2])], 1);
    }
}

// exclusive prefix over 32768 bins; 1024 threads x 32 (two-pass, no reg array).
__global__ void scan_bins(const int* __restrict__ binCnt,
                          int* __restrict__ binCur) {
    __shared__ int wsum[16];
    const int t = threadIdx.x, lane = t & 63, wv = t >> 6;
    int s = 0;
    for (int j = 0; j < 32; ++j) s += binCnt[32*t + j];
    int incl = s;
    #pragma unroll
    for (int off = 1; off < 64; off <<= 1) {
        int o = __shfl_up(incl, off, 64);
        if (lane >= off) incl += o;
    }
    if (lane == 63) wsum[wv] = incl;
    __syncthreads();
    if (t == 0) {
        int acc = 0;
        for (int w = 0; w < 16; ++w) { int x = wsum[w]; wsum[w] = acc; acc += x; }
    }
    __syncthreads();
    int run = incl - s + wsum[wv];
    for (int j = 0; j < 32; ++j) {
        const int v = binCnt[32*t + j];
        binCur[32*t + j] = run;
        run += v;
    }
}

__global__ void scatter_bins(const float* __restrict__ pc,
                             float4* __restrict__ pk,
                             int* __restrict__ binCur, int N) {
    const int t = blockIdx.x * blockDim.x + threadIdx.x;
    const int base = t * 4;
    if (base + 3 < N) {
        const float4* p4 = (const float4*)pc;
        const float4 a = p4[3*t+0], b = p4[3*t+1], c = p4[3*t+2];
        float x[4] = {a.x, a.w, b.z, c.y};
        float y[4] = {a.y, b.x, b.w, c.z};
        float z[4] = {a.z, b.y, c.x, c.w};
        #pragma unroll
        for (int q = 0; q < 4; ++q) {
            const int pos = atomicAdd(&binCur[bin_of(x[q], y[q], z[q])], 1);
            float4 v; v.x = x[q]; v.y = y[q]; v.z = z[q];
            v.w = __int_as_float(base + q);
            pk[pos] = v;
        }
    } else {
        for (int i = base; i < N; ++i) {
            const float xx = pc[3*i], yy = pc[3*i+1], zz = pc[3*i+2];
            const int pos = atomicAdd(&binCur[bin_of(xx, yy, zz)], 1);
            float4 v; v.x = xx; v.y = yy; v.z = zz; v.w = __int_as_float(i);
            pk[pos] = v;
        }
    }
}

__global__ void pack_identity(const float* __restrict__ pc,
                              float4* __restrict__ pk, int N) {
    const int i = blockIdx.x * blockDim.x + threadIdx.x;
    if (i < N) {
        float4 v; v.x = pc[3*i+0]; v.y = pc[3*i+1]; v.z = pc[3*i+2];
        v.w = __int_as_float(i);
        pk[i] = v;
    }
}

// One block per target. G = ceil(N/64) groups of 64 consecutive sorted points
// (1 point per lane). Tiers: group-classified scans -> solo tail (wave 0).
template <bool PK>
__global__ __launch_bounds__(BLOCK) void convex_plane_kernel(
    const float* __restrict__ pc, const float4* __restrict__ pk,
    const float* __restrict__ tg, float* __restrict__ out,
    int N, int M, int G)
{
    extern __shared__ uint32_t smem[];
    const int tid  = threadIdx.x;
    const int lane = tid & 63;
    const int wv   = tid >> 6;
    const int m    = blockIdx.x;

    uint32_t* mask  = smem;                         // [2G] live bits
    uint32_t* qab   = mask + 2 * G;                 // [3G] quantized AABB
    float*    cdm   = (float*)(qab + 3 * G);        // [G] cached min d2
    int*      cim   = (int*)(cdm + G);              // [G] cached argmin (orig)
    int*      ccn   = cim + G;                      // [G] cached live count
    int*      blist = ccn + G;                      // [G] boundary group ids
    int*      bcnt  = blist + G;                    // [1]
    float*    red_d = (float*)(bcnt + 1);           // [NW]
    int*      red_i = (int*)(red_d + NW);           // [NW]
    int*      cw    = red_i + NW;                   // [NW]
    int*      bcast = cw + NW;                      // [2]
    int*      cnt   = bcast + 2;                    // [1]
    int*      slist = cnt + 1;                      // [SOLO_CAP]
    float*    lx    = (float*)(slist + SOLO_CAP);   // [SOLO_CAP] x3
    float*    ly    = lx + SOLO_CAP;
    float*    lz    = ly + SOLO_CAP;

    const float tx = tg[3*m+0], ty = tg[3*m+1], tz = tg[3*m+2];
    const float t2 = tx*tx + ty*ty + tz*tz;

    float* out_a = out;
    float* out_b = out + (size_t)MAX_ITERS * (size_t)M * 3;

    auto ldpt = [&](int g, float& x, float& y, float& z, int& ov) {
        int ip = g * 64 + lane;
        ip = ip < N ? ip : N - 1;                   // clamped, unconditional
        if constexpr (PK) {
            const float4 v = pk[ip];
            x = v.x; y = v.y; z = v.z; ov = __float_as_int(v.w);
        } else {
            const float* p = pc + 3 * (size_t)ip;
            x = p[0]; y = p[1]; z = p[2]; ov = ip;
        }
    };

    // outward quantization, +-1 index guard for fp rounding of the scale mul
    auto qdn = [](float v) -> uint32_t {
        int q = (int)floorf((v + 16.f) * QSC) - 1;
        return (uint32_t)(q < 0 ? 0 : (q > 65535 ? 65535 : q));
    };
    auto qup = [](float v) -> uint32_t {
        int q = (int)ceilf((v + 16.f) * QSC) + 1;
        return (uint32_t)(q < 0 ? 0 : (q > 65535 ? 65535 : q));
    };

    // reduce wave state for group g and store mask + cached state + AABB.
    auto writeGroup = [&](int g, bool keep, float x, float y, float z,
                          float d2, int ov) {
        unsigned long long bal = __ballot(keep);
        if (lane == 0)       mask[2*g]     = (uint32_t)bal;
        else if (lane == 32) mask[2*g + 1] = (uint32_t)(bal >> 32);
        float dmin = keep ? d2 : INFINITY;
        int   imin = keep ? ov : 0;
        float nx = keep ? x :  INFINITY, Xx = keep ? x : -INFINITY;
        float ny = keep ? y :  INFINITY, Xy = keep ? y : -INFINITY;
        float nz = keep ? z :  INFINITY, Xz = keep ? z : -INFINITY;
        #pragma unroll
        for (int off = 32; off > 0; off >>= 1) {
            float od = __shfl_down(dmin, off, 64);
            int   oi = __shfl_down(imin, off, 64);
            if (od < dmin || (od == dmin && oi < imin)) { dmin = od; imin = oi; }
            nx = fminf(nx, __shfl_down(nx, off, 64));
            ny = fminf(ny, __shfl_down(ny, off, 64));
            nz = fminf(nz, __shfl_down(nz, off, 64));
            Xx = fmaxf(Xx, __shfl_down(Xx, off, 64));
            Xy = fmaxf(Xy, __shfl_down(Xy, off, 64));
            Xz = fmaxf(Xz, __shfl_down(Xz, off, 64));
        }
        if (lane == 0) {
            const int c = (int)__popcll(bal);
            cdm[g] = dmin; cim[g] = imin; ccn[g] = c;
            uint32_t q0, q1, q2;
            const bool fits = (c == 0) ||
                (nx > -15.9f && Xx < 15.9f && ny > -15.9f && Xy < 15.9f &&
                 nz > -15.9f && Xz < 15.9f);
            if (fits) {
                const uint32_t a = qdn(nx), b2 = qdn(ny), c2 = qdn(nz);
                const uint32_t d = qup(Xx), e = qup(Xy), f = qup(Xz);
                q0 = a | (b2 << 16); q1 = c2 | (d << 16); q2 = e | (f << 16);
            } else {                                 // sentinel: mnx_q > mxx_q
                q0 = 1u; q1 = 0u; q2 = 0u;           // -> always boundary
            }
            qab[3*g] = q0; qab[3*g+1] = q1; qab[3*g+2] = q2;
        }
    };

    // exact per-point retest of a boundary group (mask-gated).
    auto procGroup = [&](int g, float x, float y, float z, int ov,
                         float ax, float ay, float az, float b) {
        const uint32_t w = mask[2*g + (lane >> 5)];
        const bool live = (w >> (lane & 31)) & 1u;
        bool keep = false; float d2 = INFINITY;
        if (live) {
            float dt = ax*x + ay*y + az*z - b;
            if (dt < EPS_SEP) {                      // !(dt >= EPS_SEP)
                keep = true;
                float p2 = x*x + y*y + z*z;
                float tp = tx*x + ty*y + tz*z;
                d2 = t2 + p2 - 2.0f*tp;              // reference's exact form
            }
        }
        writeGroup(g, keep, x, y, z, d2, ov);
    };

    // block argmin+count over cached per-group state.
    auto finish = [&]() -> int2 {
        __syncthreads();                             // group writes visible
        float bd = INFINITY; int bi = 0; int cs = 0;
        for (int g = tid; g < G; g += BLOCK) {       // consecutive: no conflicts
            const float d = cdm[g]; const int i = cim[g];
            if (d < bd || (d == bd && i < bi)) { bd = d; bi = i; }
            cs += ccn[g];
        }
        #pragma unroll
        for (int off = 32; off > 0; off >>= 1) {
            float od = __shfl_down(bd, off, 64);
            int   oi = __shfl_down(bi, off, 64);
            int   oc = __shfl_down(cs, off, 64);
            if (od < bd || (od == bd && oi < bi)) { bd = od; bi = oi; }
            cs += oc;
        }
        if (lane == 0) { red_d[wv] = bd; red_i[wv] = bi; cw[wv] = cs; }
        __syncthreads();
        if (wv == 0) {
            float d = (lane < NW) ? red_d[lane] : INFINITY;
            int   i = (lane < NW) ? red_i[lane] : 0;
            int   c = (lane < NW) ? cw[lane]    : 0;
            #pragma unroll
            for (int off = 8; off > 0; off >>= 1) {
                float od = __shfl_down(d, off, 64);
                int   oi = __shfl_down(i, off, 64);
                int   oc = __shfl_down(c, off, 64);
                if (od < d || (od == d && oi < i)) { d = od; i = oi; }
                c += oc;
            }
            if (lane == 0) { bcast[0] = i; bcast[1] = c; }
        }
        __syncthreads();
        int2 r; r.x = bcast[0]; r.y = bcast[1];
        return r;
    };

    // init: all in-range live; per-group AABB + argmin/count.
    for (int g = wv; g < G; g += NW) {
        float x, y, z; int ov;
        ldpt(g, x, y, z, ov);
        const bool live = (g * 64 + lane) < N;
        float d2 = INFINITY;
        if (live) {
            float p2 = x*x + y*y + z*z;
            float tp = tx*x + ty*y + tz*z;
            d2 = t2 + p2 - 2.0f*tp;                  // exact reference form
        }
        writeGroup(g, live, x, y, z, d2, ov);
    }
    int2 rc = finish();
    int idx = rc.x, count = rc.y;

    for (int k = 0; k < MAX_ITERS; ++k) {
        // Solo endgame: compact survivors to LDS coords, wave 0 finishes.
        if (count <= SOLO_CAP && count > 0) {
            if (tid == 0) cnt[0] = 0;
            __syncthreads();
            for (int g = wv; g < G; g += NW) {
                if (ccn[g] == 0) continue;           // wave-uniform
                float x, y, z; int ov;
                ldpt(g, x, y, z, ov);
                const uint32_t w = mask[2*g + (lane >> 5)];
                const bool live = (w >> (lane & 31)) & 1u;
                unsigned long long bal = __ballot(live);
                const int tot = (int)__popcll(bal);
                int wb = 0;
                if (lane == 0) wb = atomicAdd(cnt, tot);
                wb = __shfl(wb, 0, 64);
                const int pos = wb + (int)__popcll(bal & ((1ull << lane) - 1ull));
                if (live) { slist[pos] = ov; lx[pos] = x; ly[pos] = y; lz[pos] = z; }
            }
            __syncthreads();
            if (wv != 0) return;                     // LDS persists
            for (; k < MAX_ITERS; ++k) {
                const float* cp = pc + 3 * (size_t)idx;
                const float cx = cp[0], cy = cp[1], cz = cp[2];
                const float vx = cx - tx, vy = cy - ty, vz = cz - tz;
                const float nrm = sqrtf(vx*vx + vy*vy + vz*vz);
                const float den = nrm + EPS_NORM;
                const float ax = vx / den, ay = vy / den, az = vz / den;
                const float b  = ax*cx + ay*cy + az*cz;
                if (count == 0) {                    // constant tail
                    for (int q = lane; q < MAX_ITERS - k; q += 64) {
                        const int kk = k + q;
                        const size_t oa = ((size_t)kk * M + m) * 3;
                        out_a[oa+0] = ax; out_a[oa+1] = ay; out_a[oa+2] = az;
                        out_b[(size_t)kk * M + m] = b;
                    }
                    return;
                }
                if (lane == 0) {
                    const size_t oa = ((size_t)k * M + m) * 3;
                    out_a[oa+0] = ax; out_a[oa+1] = ay; out_a[oa+2] = az;
                    out_b[(size_t)k * M + m] = b;
                }
                if (k + 1 < MAX_ITERS) {
                    float dmin = INFINITY; int imin = 0; int wcur = 0;
                    for (int e0 = 0; e0 < count; e0 += 64) {
                        const int e = e0 + lane;
                        bool keep = false; int j = 0;
                        float d2v = 0.f, px = 0.f, py = 0.f, pz = 0.f;
                        if (e < count) {
                            j = slist[e];
                            px = lx[e]; py = ly[e]; pz = lz[e];
                            float dt = ax*px + ay*py + az*pz - b;
                            if (dt < EPS_SEP) {
                                keep = true;
                                float p2 = px*px + py*py + pz*pz;
                                float tp = tx*px + ty*py + tz*pz;
                                d2v = t2 + p2 - 2.0f*tp;
                            }
                        }
                        // in-place compact: pos < wcur+64 <= e0+64; chunk
                        // [e0,e0+64) already in registers.
                        unsigned long long bal = __ballot(keep);
                        int pos = wcur + (int)__popcll(bal & ((1ull << lane) - 1ull));
                        if (keep) {
                            slist[pos] = j;
                            lx[pos] = px; ly[pos] = py; lz[pos] = pz;
                            if (d2v < dmin || (d2v == dmin && j < imin)) {
                                dmin = d2v; imin = j;
                            }
                        }
                        wcur += (int)__popcll(bal);
                    }
                    #pragma unroll
                    for (int off = 32; off > 0; off >>= 1) {
                        float od = __shfl_down(dmin, off, 64);
                        int   oi = __shfl_down(imin, off, 64);
                        if (od < dmin || (od == dmin && oi < imin)) { dmin = od; imin = oi; }
                    }
                    idx = __shfl(imin, 0, 64);
                    count = wcur;
                }
            }
            return;
        }

        const float* cp = pc + 3 * (size_t)idx;      // idx = ORIGINAL index
        const float cx = cp[0], cy = cp[1], cz = cp[2];
        const float vx = cx - tx, vy = cy - ty, vz = cz - tz;
        const float nrm = sqrtf(vx*vx + vy*vy + vz*vz);
        const float den = nrm + EPS_NORM;
        const float ax = vx / den, ay = vy / den, az = vz / den;
        const float b  = ax*cx + ay*cy + az*cz;      // b = sum(a * closest)

        if (count == 0) {                            // constant tail
            for (int q = tid; q < MAX_ITERS - k; q += BLOCK) {
                const int kk = k + q;
                const size_t oa = ((size_t)kk * M + m) * 3;
                out_a[oa+0] = ax; out_a[oa+1] = ay; out_a[oa+2] = az;
                out_b[(size_t)kk * M + m] = b;
            }
            return;
        }
        if (tid == 0) {
            const size_t oa = ((size_t)k * M + m) * 3;
            out_a[oa+0] = ax; out_a[oa+1] = ay; out_a[oa+2] = az;
            out_b[(size_t)k * M + m] = b;
        }
        if (k + 1 < MAX_ITERS) {                     // last update unobservable
            // --- classify all groups (lane-parallel scalar) ---
            if (tid == 0) bcnt[0] = 0;
            __syncthreads();
            for (int g = tid; g < G; g += BLOCK) {
                int cls = 0;                         // 0 keep/skip, 1 die, 2 bnd
                if (ccn[g] > 0) {
                    const uint32_t q0 = qab[3*g], q1 = qab[3*g+1], q2 = qab[3*g+2];
                    const int mnxq = q0 & 0xFFFF, mnyq = q0 >> 16;
                    const int mnzq = q1 & 0xFFFF, mxxq = q1 >> 16;
                    const int mxyq = q2 & 0xFFFF, mxzq = q2 >> 16;
                    if (mnxq > mxxq) cls = 2;        // sentinel: out-of-range
                    else {
                        const float mnx = mnxq*QIN - 16.f, mny = mnyq*QIN - 16.f;
                        const float mnz = mnzq*QIN - 16.f, mxx = mxxq*QIN - 16.f;
                        const float mxy = mxyq*QIN - 16.f, mxz = mxzq*QIN - 16.f;
                        const float ub = fmaxf(ax*mnx, ax*mxx)
                                       + fmaxf(ay*mny, ay*mxy)
                                       + fmaxf(az*mnz, az*mxz) - b;
                        if (ub + SLACK < EPS_SEP) cls = 0;        // all keep
                        else {
                            const float lb = fminf(ax*mnx, ax*mxx)
                                           + fminf(ay*mny, ay*mxy)
                                           + fminf(az*mnz, az*mxz) - b;
                            cls = (lb - SLACK >= EPS_SEP) ? 1 : 2;
                        }
                    }
                }
                if (cls == 1) { ccn[g] = 0; cdm[g] = INFINITY; } // sole writer
                unsigned long long bal = __ballot(cls == 2);
                if (bal) {
                    const int leader = (int)(__ffsll(bal) - 1);
                    const int tot = (int)__popcll(bal);
                    int base = 0;
                    if (lane == leader) base = atomicAdd(bcnt, tot);
                    base = __shfl(base, leader, 64);
                    if (cls == 2)
                        blist[base + (int)__popcll(bal & ((1ull << lane) - 1ull))] = g;
                }
            }
            __syncthreads();                         // blist complete
            // --- rescan boundary groups, 2 in flight per wave ---
            const int nb = bcnt[0];
            for (int i = 2 * wv; i < nb; i += 2 * NW) {
                const int g0 = blist[i];
                const bool has1 = (i + 1) < nb;
                const int g1 = has1 ? blist[i + 1] : g0;
                float x0, y0, z0, x1, y1, z1; int o0, o1;
                ldpt(g0, x0, y0, z0, o0);            // both loads issued
                ldpt(g1, x1, y1, z1, o1);            // before any use
                procGroup(g0, x0, y0, z0, o0, ax, ay, az, b);
                if (has1) procGroup(g1, x1, y1, z1, o1, ax, ay, az, b);
            }
            rc = finish();
            idx = rc.x; count = rc.y;
        }
    }
}

extern "C" void kernel_launch(void* const* d_in, const int* in_sizes, int n_in,
                              void* d_out, int out_size, void* d_ws, size_t ws_size,
                              hipStream_t stream) {
    const float* pc = (const float*)d_in[0];
    const float* tg = (const float*)d_in[1];
    float* out = (float*)d_out;
    const int N = in_sizes[0] / 3;
    const int M = in_sizes[1] / 3;
    const int G = (N + 63) / 64;

    // LDS: mask 2G + qab 3G + cdm/cim/ccn/blist 4G + bcnt 1 + red 3*NW +
    //      bcast 2 + cnt 1 + solo 4*SOLO_CAP  (~145 KB at N=200k)
    const size_t smemW = 9ull * G + 1 + 3 * NW + 2 + 1 + 4ull * SOLO_CAP;
    const size_t smem  = smemW * sizeof(uint32_t);
    const size_t pkB   = (size_t)N * sizeof(float4);
    const size_t binB  = 2 * (size_t)NBINS * sizeof(int);

    int wsmode = 0;                                  // 0 raw, 1 identity, 2 sorted
    if (d_ws && ws_size >= pkB + binB) wsmode = 2;
    else if (d_ws && ws_size >= pkB)   wsmode = 1;
    float4* pk     = (float4*)d_ws;
    int*    binCnt = (int*)((char*)d_ws + pkB);
    int*    binCur = binCnt + NBINS;

    hipFuncSetAttribute((const void*)convex_plane_kernel<true>,
                        hipFuncAttributeMaxDynamicSharedMemorySize, (int)smem);
    hipFuncSetAttribute((const void*)convex_plane_kernel<false>,
                        hipFuncAttributeMaxDynamicSharedMemorySize, (int)smem);

    if (wsmode == 2) {
        const int tpb = 256;
        const int vthreads = (N + 3) / 4;
        hipMemsetAsync(binCnt, 0, NBINS * sizeof(int), stream);
        hist_bins<<<(vthreads + tpb - 1) / tpb, tpb, 0, stream>>>(pc, binCnt, N);
        scan_bins<<<1, 1024, 0, stream>>>(binCnt, binCur);
        scatter_bins<<<(vthreads + tpb - 1) / tpb, tpb, 0, stream>>>(pc, pk,
                                                                     binCur, N);
        convex_plane_kernel<true><<<M, BLOCK, smem, stream>>>(
            pc, pk, tg, out, N, M, G);
    } else if (wsmode == 1) {
        pack_identity<<<(N + 255) / 256, 256, 0, stream>>>(pc, pk, N);
        convex_plane_kernel<true><<<M, BLOCK, smem, stream>>>(
            pc, pk, tg, out, N, M, G);
    } else {
        convex_plane_kernel<false><<<M, BLOCK, smem, stream>>>(
            pc, nullptr, tg, out, N, M, G);
    }
}

// Round 9
// 748.915 us; speedup vs baseline: 1.4159x; 1.4159x over previous
//
#include <hip/hip_runtime.h>
#include <stdint.h>
#include <math.h>

// Match numpy's non-fused multiply-add rounding in distance/plane tests.
// All d2 / plane expressions keep exactly these forms (contract off file-wide);
// p2 everywhere is x*x+y*y+z*z — bit-identical to reference. AABB
// classification is a conservative ROUTER only (exact f32 static boxes,
// SLACK >> fp error): every consumed value comes from exact per-point forms.
#pragma clang fp contract(off)

#define BLOCK 1024
#define NW 16                   // waves per block
#define MAX_ITERS 50
#define SOLO_CAP 2048
#define NBINS 32768             // 32^3 Morton bins
#define EPS_NORM 1e-8f
#define EPS_SEP (-1e-6f)
#define SLACK 1e-3f             // classify margin >> ~1e-5 fp error

// R14 synthesis of R1..R8 post-mortems:
//  - loads: 8-in-flight dwordx4 or bust (R1/R5; R8's 1-load groups = 966us).
//  - survivor state in LDS; ONE shared read-only array (R3/R4).
//  - runtime == straggler's pass bill (R11); classification needs 64-pt
//    granularity (R7) but must not pay dynamic AABB re-reductions (R8).
// Fix: STATIC subgroup boxes (64 consecutive sorted pts), computed ONCE in
// prep, stored global (100KB, L2-hot, shared by all blocks). Per iter:
// thread-parallel classify (die -> zero wholesale; straddle -> compacted
// list), then waves rescan listed subgroups 8-IN-FLIGHT with only a 12-step
// (dmin,imin) reduction each (count = popc(ballot)). Prep = 2 launches
// (fused single-block sort + parallel boxes) vs R6's 4-node ~145us chain.
__device__ __forceinline__ int bin_of(float x, float y, float z) {
    int cx = (int)floorf((x + 3.5f) * (32.0f / 7.0f));
    int cy = (int)floorf((y + 3.5f) * (32.0f / 7.0f));
    int cz = (int)floorf((z + 3.5f) * (32.0f / 7.0f));
    cx = cx < 0 ? 0 : (cx > 31 ? 31 : cx);
    cy = cy < 0 ? 0 : (cy > 31 ? 31 : cy);
    cz = cz < 0 ? 0 : (cz > 31 ? 31 : cz);
    int code = 0;
    #pragma unroll
    for (int b = 0; b < 5; ++b) {
        code |= ((cx >> b) & 1) << (3 * b);
        code |= ((cy >> b) & 1) << (3 * b + 1);
        code |= ((cz >> b) & 1) << (3 * b + 2);
    }
    return code;
}

// Single-block fused counting sort: LDS histogram -> prefix -> scatter.
// One launch instead of R6's memset+hist+scan+scatter chain.
__global__ __launch_bounds__(BLOCK) void sort_all(
    const float* __restrict__ pc, float4* __restrict__ pk, int N)
{
    extern __shared__ int hist[];                   // [NBINS + 16]
    int* wsum = hist + NBINS;
    const int t = threadIdx.x, lane = t & 63, wv = t >> 6;

    for (int i = t; i < NBINS; i += BLOCK) hist[i] = 0;
    __syncthreads();

    const int npacks = N / 4;                       // 4 pts = 3 float4
    const float4* p4 = (const float4*)pc;
    for (int p = t; p < npacks; p += BLOCK) {
        const float4 a = p4[3*p+0], b = p4[3*p+1], c = p4[3*p+2];
        atomicAdd(&hist[bin_of(a.x, a.y, a.z)], 1);
        atomicAdd(&hist[bin_of(a.w, b.x, b.y)], 1);
        atomicAdd(&hist[bin_of(b.z, b.w, c.x)], 1);
        atomicAdd(&hist[bin_of(c.y, c.z, c.w)], 1);
    }
    if (t == 0)
        for (int i = npacks * 4; i < N; ++i)
            atomicAdd(&hist[bin_of(pc[3*i], pc[3*i+1], pc[3*i+2])], 1);
    __syncthreads();

    // exclusive prefix: thread t owns bins [32t, 32t+32)
    int s = 0;
    for (int j = 0; j < 32; ++j) s += hist[32*t + j];
    int incl = s;
    #pragma unroll
    for (int off = 1; off < 64; off <<= 1) {
        int o = __shfl_up(incl, off, 64);
        if (lane >= off) incl += o;
    }
    if (lane == 63) wsum[wv] = incl;
    __syncthreads();
    if (t == 0) {
        int acc = 0;
        for (int w = 0; w < 16; ++w) { int x = wsum[w]; wsum[w] = acc; acc += x; }
    }
    __syncthreads();
    int run = incl - s + wsum[wv];
    for (int j = 0; j < 32; ++j) {
        const int v = hist[32*t + j];
        hist[32*t + j] = run;                       // hist becomes cursor
        run += v;
    }
    __syncthreads();

    for (int p = t; p < npacks; p += BLOCK) {
        const float4 a = p4[3*p+0], b = p4[3*p+1], c = p4[3*p+2];
        const float x[4] = {a.x, a.w, b.z, c.y};
        const float y[4] = {a.y, b.x, b.w, c.z};
        const float z[4] = {a.z, b.y, c.x, c.w};
        #pragma unroll
        for (int q = 0; q < 4; ++q) {
            const int pos = atomicAdd(&hist[bin_of(x[q], y[q], z[q])], 1);
            float4 v; v.x = x[q]; v.y = y[q]; v.z = z[q];
            v.w = __int_as_float(p * 4 + q);
            pk[pos] = v;
        }
    }
    if (t == 0) {
        for (int i = npacks * 4; i < N; ++i) {
            const float xx = pc[3*i], yy = pc[3*i+1], zz = pc[3*i+2];
            const int pos = atomicAdd(&hist[bin_of(xx, yy, zz)], 1);
            float4 v; v.x = xx; v.y = yy; v.z = zz; v.w = __int_as_float(i);
            pk[pos] = v;
        }
    }
}

// Static subgroup boxes: one wave per 64 consecutive sorted points.
// boxes stride 8 floats: {nx,ny,nz,Xx,Xy,Xz,pad,pad} (16B-aligned float4 x2).
__global__ void calc_boxes(const float4* __restrict__ pk,
                           float* __restrict__ boxes, int N, int G)
{
    const int g = blockIdx.x * (blockDim.x >> 6) + (threadIdx.x >> 6);
    if (g >= G) return;
    const int lane = threadIdx.x & 63;
    int ip = g * 64 + lane;
    ip = ip < N ? ip : N - 1;                       // dup of N-1 is in-group
    const float4 v = pk[ip];
    float nx = v.x, ny = v.y, nz = v.z, Xx = v.x, Xy = v.y, Xz = v.z;
    #pragma unroll
    for (int off = 32; off > 0; off >>= 1) {
        nx = fminf(nx, __shfl_down(nx, off, 64));
        ny = fminf(ny, __shfl_down(ny, off, 64));
        nz = fminf(nz, __shfl_down(nz, off, 64));
        Xx = fmaxf(Xx, __shfl_down(Xx, off, 64));
        Xy = fmaxf(Xy, __shfl_down(Xy, off, 64));
        Xz = fmaxf(Xz, __shfl_down(Xz, off, 64));
    }
    if (lane == 0) {
        float* o = boxes + 8 * (size_t)g;
        o[0] = nx; o[1] = ny; o[2] = nz; o[3] = Xx; o[4] = Xy; o[5] = Xz;
    }
}

__global__ void pack_identity(const float* __restrict__ pc,
                              float4* __restrict__ pk, int N) {
    const int i = blockIdx.x * blockDim.x + threadIdx.x;
    if (i < N) {
        float4 v; v.x = pc[3*i+0]; v.y = pc[3*i+1]; v.z = pc[3*i+2];
        v.w = __int_as_float(i);
        pk[i] = v;
    }
}

// One block per target. G subgroups of 64 consecutive sorted points.
// Tiers: static-box classified rescans -> solo tail (wave 0).
template <bool PK>
__global__ __launch_bounds__(BLOCK) void convex_plane_kernel(
    const float* __restrict__ pc, const float4* __restrict__ pk,
    const float* __restrict__ boxes, const float* __restrict__ tg,
    float* __restrict__ out, int N, int M, int G)
{
    extern __shared__ uint32_t smem[];
    const int tid  = threadIdx.x;
    const int lane = tid & 63;
    const int wv   = tid >> 6;
    const int m    = blockIdx.x;

    uint32_t* mask  = smem;                         // [2G] live bits
    float*    sdm   = (float*)(mask + 2 * G);       // [G] cached min d2
    int*      sim   = (int*)(sdm + G);              // [G] cached argmin (orig)
    int*      scn   = sim + G;                      // [G] cached live count
    int*      blist = scn + G;                      // [G] straddle group ids
    int*      bcnt  = blist + G;                    // [1]
    float*    red_d = (float*)(bcnt + 1);           // [NW]
    int*      red_i = (int*)(red_d + NW);           // [NW]
    int*      cw    = red_i + NW;                   // [NW]
    int*      bcast = cw + NW;                      // [2]
    int*      cnt   = bcast + 2;                    // [1]
    int*      slist = cnt + 1;                      // [SOLO_CAP]
    float*    lx    = (float*)(slist + SOLO_CAP);   // [SOLO_CAP] x3
    float*    ly    = lx + SOLO_CAP;
    float*    lz    = ly + SOLO_CAP;

    const float tx = tg[3*m+0], ty = tg[3*m+1], tz = tg[3*m+2];
    const float t2 = tx*tx + ty*ty + tz*tz;

    float* out_a = out;
    float* out_b = out + (size_t)MAX_ITERS * (size_t)M * 3;

    auto ldpt = [&](int g) -> float4 {              // clamped, unconditional
        int ip = g * 64 + lane;
        ip = ip < N ? ip : N - 1;
        if constexpr (PK) {
            return pk[ip];
        } else {
            const float* p = pc + 3 * (size_t)ip;
            float4 v; v.x = p[0]; v.y = p[1]; v.z = p[2];
            v.w = __int_as_float(ip);
            return v;
        }
    };

    // reduce & store subgroup state: mask bits + (dmin, imin, count).
    auto writeSub = [&](int g, bool keep, float d2, int ov) {
        unsigned long long bal = __ballot(keep);
        if (lane == 0)       mask[2*g]     = (uint32_t)bal;
        else if (lane == 32) mask[2*g + 1] = (uint32_t)(bal >> 32);
        float dmin = keep ? d2 : INFINITY;
        int   imin = keep ? ov : 0;
        #pragma unroll
        for (int off = 32; off > 0; off >>= 1) {
            float od = __shfl_down(dmin, off, 64);
            int   oi = __shfl_down(imin, off, 64);
            if (od < dmin || (od == dmin && oi < imin)) { dmin = od; imin = oi; }
        }
        if (lane == 0) {
            sdm[g] = dmin; sim[g] = imin; scn[g] = (int)__popcll(bal);
        }
    };

    // block argmin+count over cached per-subgroup state (consecutive reads).
    auto finish = [&]() -> int2 {
        __syncthreads();                            // subgroup writes visible
        float bd = INFINITY; int bi = 0; int cs = 0;
        for (int g = tid; g < G; g += BLOCK) {
            const float d = sdm[g]; const int i = sim[g];
            if (d < bd || (d == bd && i < bi)) { bd = d; bi = i; }
            cs += scn[g];
        }
        #pragma unroll
        for (int off = 32; off > 0; off >>= 1) {
            float od = __shfl_down(bd, off, 64);
            int   oi = __shfl_down(bi, off, 64);
            int   oc = __shfl_down(cs, off, 64);
            if (od < bd || (od == bd && oi < bi)) { bd = od; bi = oi; }
            cs += oc;
        }
        if (lane == 0) { red_d[wv] = bd; red_i[wv] = bi; cw[wv] = cs; }
        __syncthreads();
        if (wv == 0) {
            float d = (lane < NW) ? red_d[lane] : INFINITY;
            int   i = (lane < NW) ? red_i[lane] : 0;
            int   c = (lane < NW) ? cw[lane]    : 0;
            #pragma unroll
            for (int off = 8; off > 0; off >>= 1) {
                float od = __shfl_down(d, off, 64);
                int   oi = __shfl_down(i, off, 64);
                int   oc = __shfl_down(c, off, 64);
                if (od < d || (od == d && oi < i)) { d = od; i = oi; }
                c += oc;
            }
            if (lane == 0) { bcast[0] = i; bcast[1] = c; }
        }
        __syncthreads();
        int2 r; r.x = bcast[0]; r.y = bcast[1];
        return r;
    };

    // init: 8 subgroups (one chunk) in flight per wave (PT=8 MLP).
    for (int g8 = wv * 8; g8 < G; g8 += NW * 8) {
        float4 v[8];
        #pragma unroll
        for (int j = 0; j < 8; ++j) {
            const int g = g8 + j;
            v[j] = ldpt(g < G ? g : G - 1);         // loads all issued up front
        }
        #pragma unroll
        for (int j = 0; j < 8; ++j) {
            const int g = g8 + j;
            if (g >= G) break;                      // wave-uniform
            const bool live = (g * 64 + lane) < N;
            float d2 = INFINITY;
            const int ov = __float_as_int(v[j].w);
            if (live) {
                const float x = v[j].x, y = v[j].y, z = v[j].z;
                float p2 = x*x + y*y + z*z;
                float tp = tx*x + ty*y + tz*z;
                d2 = t2 + p2 - 2.0f*tp;             // exact reference form
            }
            writeSub(g, live, d2, ov);
        }
    }
    int2 rc = finish();
    int idx = rc.x, count = rc.y;

    for (int k = 0; k < MAX_ITERS; ++k) {
        // Solo endgame: compact survivors to LDS coords, wave 0 finishes.
        if (count <= SOLO_CAP && count > 0) {
            if (tid == 0) cnt[0] = 0;
            __syncthreads();
            for (int g = wv; g < G; g += NW) {
                if (scn[g] == 0) continue;          // wave-uniform
                const float4 v = ldpt(g);
                const uint32_t w = mask[2*g + (lane >> 5)];
                const bool live = (w >> (lane & 31)) & 1u;
                unsigned long long bal = __ballot(live);
                const int tot = (int)__popcll(bal);
                int wb = 0;
                if (lane == 0) wb = atomicAdd(cnt, tot);
                wb = __shfl(wb, 0, 64);
                const int pos = wb + (int)__popcll(bal & ((1ull << lane) - 1ull));
                if (live) {
                    slist[pos] = __float_as_int(v.w);
                    lx[pos] = v.x; ly[pos] = v.y; lz[pos] = v.z;
                }
            }
            __syncthreads();
            if (wv != 0) return;                    // LDS persists
            for (; k < MAX_ITERS; ++k) {
                const float* cp = pc + 3 * (size_t)idx;
                const float cx = cp[0], cy = cp[1], cz = cp[2];
                const float vx = cx - tx, vy = cy - ty, vz = cz - tz;
                const float nrm = sqrtf(vx*vx + vy*vy + vz*vz);
                const float den = nrm + EPS_NORM;
                const float ax = vx / den, ay = vy / den, az = vz / den;
                const float b  = ax*cx + ay*cy + az*cz;
                if (count == 0) {                   // constant tail
                    for (int q = lane; q < MAX_ITERS - k; q += 64) {
                        const int kk = k + q;
                        const size_t oa = ((size_t)kk * M + m) * 3;
                        out_a[oa+0] = ax; out_a[oa+1] = ay; out_a[oa+2] = az;
                        out_b[(size_t)kk * M + m] = b;
                    }
                    return;
                }
                if (lane == 0) {
                    const size_t oa = ((size_t)k * M + m) * 3;
                    out_a[oa+0] = ax; out_a[oa+1] = ay; out_a[oa+2] = az;
                    out_b[(size_t)k * M + m] = b;
                }
                if (k + 1 < MAX_ITERS) {
                    float dmin = INFINITY; int imin = 0; int wcur = 0;
                    for (int e0 = 0; e0 < count; e0 += 64) {
                        const int e = e0 + lane;
                        bool keep = false; int j = 0;
                        float d2v = 0.f, px = 0.f, py = 0.f, pz = 0.f;
                        if (e < count) {
                            j = slist[e];
                            px = lx[e]; py = ly[e]; pz = lz[e];
                            float dt = ax*px + ay*py + az*pz - b;
                            if (dt < EPS_SEP) {
                                keep = true;
                                float p2 = px*px + py*py + pz*pz;
                                float tp = tx*px + ty*py + tz*pz;
                                d2v = t2 + p2 - 2.0f*tp;
                            }
                        }
                        // in-place compact: pos < wcur+64 <= e0+64; chunk
                        // [e0,e0+64) already in registers.
                        unsigned long long bal = __ballot(keep);
                        int pos = wcur + (int)__popcll(bal & ((1ull << lane) - 1ull));
                        if (keep) {
                            slist[pos] = j;
                            lx[pos] = px; ly[pos] = py; lz[pos] = pz;
                            if (d2v < dmin || (d2v == dmin && j < imin)) {
                                dmin = d2v; imin = j;
                            }
                        }
                        wcur += (int)__popcll(bal);
                    }
                    #pragma unroll
                    for (int off = 32; off > 0; off >>= 1) {
                        float od = __shfl_down(dmin, off, 64);
                        int   oi = __shfl_down(imin, off, 64);
                        if (od < dmin || (od == dmin && oi < imin)) { dmin = od; imin = oi; }
                    }
                    idx = __shfl(imin, 0, 64);
                    count = wcur;
                }
            }
            return;
        }

        const float* cp = pc + 3 * (size_t)idx;     // idx = ORIGINAL index
        const float cx = cp[0], cy = cp[1], cz = cp[2];
        const float vx = cx - tx, vy = cy - ty, vz = cz - tz;
        const float nrm = sqrtf(vx*vx + vy*vy + vz*vz);
        const float den = nrm + EPS_NORM;
        const float ax = vx / den, ay = vy / den, az = vz / den;
        const float b  = ax*cx + ay*cy + az*cz;     // b = sum(a * closest)

        if (count == 0) {                           // constant tail
            for (int q = tid; q < MAX_ITERS - k; q += BLOCK) {
                const int kk = k + q;
                const size_t oa = ((size_t)kk * M + m) * 3;
                out_a[oa+0] = ax; out_a[oa+1] = ay; out_a[oa+2] = az;
                out_b[(size_t)kk * M + m] = b;
            }
            return;
        }
        if (tid == 0) {
            const size_t oa = ((size_t)k * M + m) * 3;
            out_a[oa+0] = ax; out_a[oa+1] = ay; out_a[oa+2] = az;
            out_b[(size_t)k * M + m] = b;
        }
        if (k + 1 < MAX_ITERS) {                    // last update unobservable
            // --- classify all live subgroups against static boxes ---
            if (tid == 0) bcnt[0] = 0;
            __syncthreads();
            for (int g = tid; g < G; g += BLOCK) {
                int cls = 0;                        // 0 keep/skip, 1 die, 2 bnd
                if (scn[g] > 0) {
                    if (boxes) {
                        const float4 b0 = ((const float4*)boxes)[2*g];
                        const float4 b1 = ((const float4*)boxes)[2*g + 1];
                        // b0={nx,ny,nz,Xx}  b1={Xy,Xz,-,-}
                        const float ub = fmaxf(ax*b0.x, ax*b0.w)
                                       + fmaxf(ay*b0.y, ay*b1.x)
                                       + fmaxf(az*b0.z, az*b1.y) - b;
                        if (ub + SLACK < EPS_SEP) cls = 0;       // all keep
                        else {
                            const float lb = fminf(ax*b0.x, ax*b0.w)
                                           + fminf(ay*b0.y, ay*b1.x)
                                           + fminf(az*b0.z, az*b1.y) - b;
                            cls = (lb - SLACK >= EPS_SEP) ? 1 : 2;
                        }
                    } else cls = 2;                 // no boxes: always rescan
                    if (cls == 1) { scn[g] = 0; sdm[g] = INFINITY; }
                }
                unsigned long long bal = __ballot(cls == 2);
                if (bal) {
                    const int leader = (int)(__ffsll(bal) - 1);
                    const int tot = (int)__popcll(bal);
                    int base = 0;
                    if (lane == leader) base = atomicAdd(bcnt, tot);
                    base = __shfl(base, leader, 64);
                    if (cls == 2)
                        blist[base + (int)__popcll(bal & ((1ull << lane) - 1ull))] = g;
                }
            }
            __syncthreads();                        // blist complete
            // --- rescan straddle subgroups, 8 IN FLIGHT per wave ---
            const int nb = bcnt[0];
            for (int base = wv * 8; base < nb; base += NW * 8) {
                int gq[8]; float4 vq[8];
                #pragma unroll
                for (int q = 0; q < 8; ++q) {       // loads all issued up front
                    const int e = base + q;
                    const int g = blist[e < nb ? e : nb - 1];
                    gq[q] = (e < nb) ? g : -1;
                    vq[q] = ldpt(g);
                }
                #pragma unroll
                for (int q = 0; q < 8; ++q) {
                    if (gq[q] < 0) break;           // wave-uniform
                    const int g = gq[q];
                    const uint32_t w = mask[2*g + (lane >> 5)];
                    const bool live = (w >> (lane & 31)) & 1u;
                    bool keep = false; float d2 = INFINITY;
                    const int ov = __float_as_int(vq[q].w);
                    if (live) {
                        const float x = vq[q].x, y = vq[q].y, z = vq[q].z;
                        float dt = ax*x + ay*y + az*z - b;
                        if (dt < EPS_SEP) {         // !(dt >= EPS_SEP)
                            keep = true;
                            float p2 = x*x + y*y + z*z;
                            float tp = tx*x + ty*y + tz*z;
                            d2 = t2 + p2 - 2.0f*tp; // exact reference form
                        }
                    }
                    writeSub(g, keep, d2, ov);
                }
            }
            rc = finish();
            idx = rc.x; count = rc.y;
        }
    }
}

extern "C" void kernel_launch(void* const* d_in, const int* in_sizes, int n_in,
                              void* d_out, int out_size, void* d_ws, size_t ws_size,
                              hipStream_t stream) {
    const float* pc = (const float*)d_in[0];
    const float* tg = (const float*)d_in[1];
    float* out = (float*)d_out;
    const int N = in_sizes[0] / 3;
    const int M = in_sizes[1] / 3;
    const int G = (N + 63) / 64;

    // LDS: mask 2G + sdm/sim/scn/blist 4G + bcnt 1 + red 3*NW + bcast 2 +
    //      cnt 1 + solo 4*SOLO_CAP  (~108 KB at N=200k)
    const size_t smemW = 6ull * G + 1 + 3 * NW + 2 + 1 + 4ull * SOLO_CAP;
    const size_t smem  = smemW * sizeof(uint32_t);
    const size_t pkB   = (size_t)N * sizeof(float4);
    const size_t boxB  = (size_t)G * 8 * sizeof(float);
    const size_t sortSmem = (NBINS + 16) * sizeof(int);   // 128KB + 64B

    int wsmode = 0;                                 // 0 raw, 1 identity, 2 sorted
    if (d_ws && ws_size >= pkB + boxB) wsmode = 2;
    else if (d_ws && ws_size >= pkB)   wsmode = 1;
    float4* pk    = (float4*)d_ws;
    float*  boxes = (float*)((char*)d_ws + pkB);

    hipFuncSetAttribute((const void*)convex_plane_kernel<true>,
                        hipFuncAttributeMaxDynamicSharedMemorySize, (int)smem);
    hipFuncSetAttribute((const void*)convex_plane_kernel<false>,
                        hipFuncAttributeMaxDynamicSharedMemorySize, (int)smem);
    hipFuncSetAttribute((const void*)sort_all,
                        hipFuncAttributeMaxDynamicSharedMemorySize,
                        (int)sortSmem);

    if (wsmode == 2) {
        sort_all<<<1, BLOCK, sortSmem, stream>>>(pc, pk, N);
        calc_boxes<<<(G + 3) / 4, 256, 0, stream>>>(pk, boxes, N, G);
        convex_plane_kernel<true><<<M, BLOCK, smem, stream>>>(
            pc, pk, boxes, tg, out, N, M, G);
    } else if (wsmode == 1) {
        pack_identity<<<(N + 255) / 256, 256, 0, stream>>>(pc, pk, N);
        convex_plane_kernel<true><<<M, BLOCK, smem, stream>>>(
            pc, pk, nullptr, tg, out, N, M, G);
    } else {
        convex_plane_kernel<false><<<M, BLOCK, smem, stream>>>(
            pc, nullptr, nullptr, tg, out, N, M, G);
    }
}